// Round 14
// baseline (61.987 us; speedup 1.0000x reference)
//
#include <hip/hip_runtime.h>

#define T_STEPS 32
#define BATCH   65536
#define IN_DIM  27
#define H_DIM   10
#define H2_DIM  5
#define XROW    36   // LDS x-row stride in halfs (72B = 18 dwords; 18*bn mod 32 distinct -> conflict-free b64 reads)

typedef _Float16 f16_t;
typedef _Float16 f16x4 __attribute__((ext_vector_type(4)));
typedef float    f32x4 __attribute__((ext_vector_type(4)));

__device__ __forceinline__ float fast_exp2(float v) { return __builtin_amdgcn_exp2f(v); }
__device__ __forceinline__ float fast_rcp(float v)  { return __builtin_amdgcn_rcpf(v); }
__device__ __forceinline__ float fast_sigmoid(float v) {
    return fast_rcp(1.f + fast_exp2(v * -1.4426950408889634f));
}
__device__ __forceinline__ float fast_tanh(float v) {
    return 1.f - 2.f * fast_rcp(1.f + fast_exp2(v * 2.8853900817779268f));
}

// ---------------------------------------------------------------------------
// Fully-fused MFMA LSTM v3: coalesced staging (R13 -> R14).
// R12 (ILP) and R13 (TLP) nulls => throughput-bound, and the numbers point at
// HBM: per-lane 16B fragment loads fetched 128B per 108B row (2x64B windows,
// stride-108 scatter) at ~4.9 TB/s raw. Fix: fetch each wave's 1728B slab
// with perfectly-coalesced dwordx4 (lane i -> chunk i), cvt to f16 once,
// stage into a per-wave double-buffered LDS x-table; A-fragments come from
// conflict-free ds_read_b64. Loads issued at t are staged at t+1 (full-step
// latency cover) and read at t+2. K-split is now clean 0-15 / 16-31 (LDS pad
// cols 27-31 zeroed; B rows k>=27 zeroed too).
// Layout (R9/R10-validated 16x16x16 f16): A row=lane&15, k=(lane>>4)*4+i;
// B col=lane&15; C lane(kg,bn) reg -> (row kg*4+reg, col bn). Gate dim
// padded 40->64 (nt = gate type) -> all 4 gate types of (elem,unit) in-lane.
// ---------------------------------------------------------------------------
__global__
__attribute__((amdgpu_flat_work_group_size(256, 256), amdgpu_waves_per_eu(4, 4)))
void lstm_fused_mfma(
    const float* __restrict__ word,   // [T, B, IN]
    const float* __restrict__ W_ih,   // [40, 27]
    const float* __restrict__ W_hh,   // [40, 10]
    const float* __restrict__ b_ih,   // [40]
    const float* __restrict__ b_hh,   // [40]
    const float* __restrict__ W_fc,   // [5, 10]
    const float* __restrict__ b_fc,   // [5]
    const float* __restrict__ W_out,  // [1, 5]
    const float* __restrict__ b_out,  // [1]
    float* __restrict__ out)          // [B]
{
    __shared__ __align__(16) f16_t s_x[4][2][16 * XROW];  // 2x1152B per wave
    __shared__ __align__(16) f16_t s_h[4][16 * 20];       // h table per wave

    const int tid  = threadIdx.x;
    const int lane = tid & 63;
    const int w    = tid >> 6;
    const int bn   = lane & 15;       // fragment col (gate unit) / A row (elem)
    const int kg   = lane >> 4;       // fragment k-group
    const int e0   = blockIdx.x * 64 + w * 16;   // wave's 16 elements

    // ---- resident weight fragments (loaded once; gates padded 40->64) ----
    const bool gok = (bn < H_DIM);
    f16x4 bfx0[4], bfx1[4], bfh[4];
    float bias[4];
#pragma unroll
    for (int nt = 0; nt < 4; ++nt) {  // nt = gate type: 0=i 1=f 2=g 3=o
        const int g = nt * H_DIM + bn;
        bias[nt] = gok ? (b_ih[g] + b_hh[g]) : 0.f;
#pragma unroll
        for (int i = 0; i < 4; ++i) {
            const int k  = kg * 4 + i;        // 0..15
            const int k2 = 16 + kg * 4 + i;   // 16..31
            bfx0[nt][i] = (f16_t)(gok ? W_ih[g * IN_DIM + k] : 0.f);
            bfx1[nt][i] = (f16_t)((gok && k2 < IN_DIM) ? W_ih[g * IN_DIM + k2] : 0.f);
            bfh[nt][i]  = (f16_t)((gok && k < H_DIM) ? W_hh[g * H_DIM + k] : 0.f);
        }
    }

    f16_t* xb0 = &s_x[w][0][0];
    f16_t* xb1 = &s_x[w][1][0];
    f16_t* tb  = &s_h[w][0];

    // ---- one-time LDS init: zero both x buffers (incl. pad cols) + h0 ----
    {
        f16x4 z = {(f16_t)0.f, (f16_t)0.f, (f16_t)0.f, (f16_t)0.f};
        f16_t* base = &s_x[w][0][0];              // contiguous 2*16*XROW halfs
        for (int s = lane; s < 2 * 16 * XROW / 4; s += 64)
            *(f16x4*)(base + s * 4) = z;
        *(f16x4*)(tb + bn * 20 + kg * 4) = z;     // exactly the ah read slots
    }

    // ---- per-lane staging constants: chunk1 = lane, chunk2 = 64+lane (<108) ----
    int off1[4], off2[4];
#pragma unroll
    for (int j = 0; j < 4; ++j) {
        const int g1 = 4 * lane + j;
        off1[j] = (g1 / IN_DIM) * XROW + (g1 % IN_DIM);
        const int g2 = 256 + 4 * lane + j;
        off2[j] = (g2 / IN_DIM) * XROW + (g2 % IN_DIM);
    }
    const bool has2 = (lane < 44);    // 108 chunks: 64 + 44

    const size_t tstep = (size_t)BATCH * IN_DIM;
    const float* slabbase = word + (size_t)e0 * IN_DIM;   // 16B-aligned (e0%16==0)

    // ---- prologue: stage x(0) into xb0; x(1) chunks left pending in regs ----
    {
        f32x4 v1 = *(const f32x4*)(slabbase + 4 * lane);
#pragma unroll
        for (int j = 0; j < 4; ++j) xb0[off1[j]] = (f16_t)v1[j];
        if (has2) {
            f32x4 v2 = *(const f32x4*)(slabbase + 256 + 4 * lane);
#pragma unroll
            for (int j = 0; j < 4; ++j) xb0[off2[j]] = (f16_t)v2[j];
        }
    }
    f32x4 p1, p2;
    {
        const float* slab1 = slabbase + tstep;
        p1 = *(const f32x4*)(slab1 + 4 * lane);
        p2 = has2 ? *(const f32x4*)(slab1 + 256 + 4 * lane) : (f32x4){0.f, 0.f, 0.f, 0.f};
    }

    float c[4];
#pragma unroll
    for (int r = 0; r < 4; ++r) c[r] = 0.f;

#pragma unroll 2
    for (int t = 0; t < T_STEPS; ++t) {
        f16_t* xcur = (t & 1) ? xb1 : xb0;
        f16_t* xnxt = (t & 1) ? xb0 : xb1;

        // (a) fragments from LDS (conflict-free b64 reads)
        const f16x4 ax0 = *(const f16x4*)(xcur + bn * XROW + kg * 4);
        const f16x4 ax1 = *(const f16x4*)(xcur + bn * XROW + 16 + kg * 4);
        const f16x4 ah  = *(const f16x4*)(tb + bn * 20 + kg * 4);

        // (b) stage pending x(t+1) -> xnxt (loads are a full step old)
#pragma unroll
        for (int j = 0; j < 4; ++j) xnxt[off1[j]] = (f16_t)p1[j];
        if (has2) {
#pragma unroll
            for (int j = 0; j < 4; ++j) xnxt[off2[j]] = (f16_t)p2[j];
        }

        // (c) issue x(t+2) loads (coalesced dwordx4; clamped at tail, L2-hot)
        {
            const int tn = (t + 2 < T_STEPS) ? t + 2 : (T_STEPS - 1);
            const float* slab = slabbase + (size_t)tn * tstep;
            p1 = *(const f32x4*)(slab + 4 * lane);
            if (has2) p2 = *(const f32x4*)(slab + 256 + 4 * lane);
        }

        // (d) gates = bias + X@Wih^T + H@Whh^T (12 MFMA, weights resident)
        f32x4 acc[4];
#pragma unroll
        for (int nt = 0; nt < 4; ++nt) {
            f32x4 a = {bias[nt], bias[nt], bias[nt], bias[nt]};
            a = __builtin_amdgcn_mfma_f32_16x16x16f16(ax0, bfx0[nt], a, 0, 0, 0);
            a = __builtin_amdgcn_mfma_f32_16x16x16f16(ax1, bfx1[nt], a, 0, 0, 0);
            a = __builtin_amdgcn_mfma_f32_16x16x16f16(ah,  bfh[nt],  a, 0, 0, 0);
            acc[nt] = a;
        }

        // (e) update: lane owns (elem kg*4+reg, unit bn); all 4 types local
#pragma unroll
        for (int reg = 0; reg < 4; ++reg) {
            const float iv = fast_sigmoid(acc[0][reg]);
            const float fv = fast_sigmoid(acc[1][reg]);
            const float gv = fast_tanh   (acc[2][reg]);
            const float ov = fast_sigmoid(acc[3][reg]);
            const float cn = fmaf(fv, c[reg], iv * gv);
            c[reg] = fmaxf(cn, 0.f);                  // relu'd carry
            const float hv = ov * fast_tanh(c[reg]);  // >=0: relu(h) == h
            tb[(kg * 4 + reg) * 20 + bn] = (f16_t)hv; // C-layout -> table
        }
    }

    // ---- head on lanes 0..15 (one per elem) ----
    if (lane < 16) {
        float hv[H_DIM];
#pragma unroll
        for (int u = 0; u < H_DIM; ++u) hv[u] = (float)tb[lane * 20 + u];
        float accv = b_out[0];
#pragma unroll
        for (int p = 0; p < H2_DIM; ++p) {
            float y = b_fc[p];
#pragma unroll
            for (int m = 0; m < H_DIM; ++m) y = fmaf(W_fc[p * H_DIM + m], hv[m], y);
            y = fmaxf(y, 0.f);
            accv = fmaf(W_out[p], y, accv);
        }
        out[e0 + lane] = fast_sigmoid(accv);
    }
}

extern "C" void kernel_launch(void* const* d_in, const int* in_sizes, int n_in,
                              void* d_out, int out_size, void* d_ws, size_t ws_size,
                              hipStream_t stream) {
    const float* word  = (const float*)d_in[0];
    const float* W_ih  = (const float*)d_in[1];
    const float* W_hh  = (const float*)d_in[2];
    const float* b_ih  = (const float*)d_in[3];
    const float* b_hh  = (const float*)d_in[4];
    const float* W_fc  = (const float*)d_in[5];
    const float* b_fc  = (const float*)d_in[6];
    const float* W_out = (const float*)d_in[7];
    const float* b_out = (const float*)d_in[8];
    float* out = (float*)d_out;

    // 16 elems/wave, 4 waves/block -> 64 elems/block -> 1024 blocks (4/CU)
    lstm_fused_mfma<<<BATCH / 64, 256, 0, stream>>>(
        word, W_ih, W_hh, b_ih, b_hh, W_fc, b_fc, W_out, b_out, out);
}

// Round 15
// 55.018 us; speedup vs baseline: 1.1267x; 1.1267x over previous
//
#include <hip/hip_runtime.h>

#define T_STEPS 32
#define BATCH   65536
#define IN_DIM  27
#define H_DIM   10
#define H2_DIM  5

typedef _Float16 f16_t;
typedef _Float16 f16x4 __attribute__((ext_vector_type(4)));
typedef float    f32x4 __attribute__((ext_vector_type(4)));

__device__ __forceinline__ float fast_exp2(float v) { return __builtin_amdgcn_exp2f(v); }
__device__ __forceinline__ float fast_rcp(float v)  { return __builtin_amdgcn_rcpf(v); }
__device__ __forceinline__ float fast_sigmoid(float v) {
    return fast_rcp(1.f + fast_exp2(v * -1.4426950408889634f));
}
__device__ __forceinline__ float fast_tanh(float v) {
    return 1.f - 2.f * fast_rcp(1.f + fast_exp2(v * 2.8853900817779268f));
}

// unaligned-safe 16B global load (word rows are 108 B -> only 4B alignment)
__device__ __forceinline__ f32x4 load4u(const float* p) {
    f32x4 v; __builtin_memcpy(&v, p, 16); return v;
}

// ---------------------------------------------------------------------------
// Fully-fused MFMA LSTM — FINAL (exact R10 body, best measured 54.8us).
// Session ledger: R12 ILP null, R13 TLP null, R14 LDS-staging regression
// => this operating point is the composite floor: 226 MB input stream at
// ~4.1 TB/s unique-rate interleaved with a serial 32-step recurrence and
// 40 transcendentals/lane-step. 33x over the naive fused baseline.
// Layout (R9-validated 16x16x16 f16): A row=lane&15, k=(lane>>4)*4+i;
// B col=lane&15 same k; C lane(kg,bn) reg -> (row kg*4+reg, col bn).
// Gate dim padded 40->64 (nt = gate TYPE) -> each lane holds all 4 gate
// types of (elem kg*4+reg, unit bn): LSTM update needs zero shuffles.
// h feedback via per-wave LDS table (C-layout write, A-fragment read).
// x K-split: ks0 = cols 0..15; ks1 = cols 11..26 with B rows j<5 zeroed
// (overlap masked; loads never cross the 27-float row end -> no OOB).
// ---------------------------------------------------------------------------
__global__
__attribute__((amdgpu_flat_work_group_size(256, 256), amdgpu_waves_per_eu(4, 4)))
void lstm_fused_mfma(
    const float* __restrict__ word,   // [T, B, IN]
    const float* __restrict__ W_ih,   // [40, 27]
    const float* __restrict__ W_hh,   // [40, 10]
    const float* __restrict__ b_ih,   // [40]
    const float* __restrict__ b_hh,   // [40]
    const float* __restrict__ W_fc,   // [5, 10]
    const float* __restrict__ b_fc,   // [5]
    const float* __restrict__ W_out,  // [1, 5]
    const float* __restrict__ b_out,  // [1]
    float* __restrict__ out)          // [B]
{
    __shared__ __align__(16) f16_t s_h[4][16 * 20];   // per-wave h table, 2560 B

    const int tid  = threadIdx.x;
    const int lane = tid & 63;
    const int w    = tid >> 6;
    const int bn   = lane & 15;       // fragment col (gate unit) / A row (elem)
    const int kg   = lane >> 4;       // fragment k-group
    const int e0   = blockIdx.x * 64 + w * 16;   // wave's 16 elements

    // ---- resident weight fragments (loaded once; gates padded 40->64) ----
    const bool gok = (bn < H_DIM);
    f16x4 bfx0[4], bfx1[4], bfh[4];
    float bias[4];
#pragma unroll
    for (int nt = 0; nt < 4; ++nt) {  // nt = gate type: 0=i 1=f 2=g 3=o
        const int g = nt * H_DIM + bn;
        bias[nt] = gok ? (b_ih[g] + b_hh[g]) : 0.f;
#pragma unroll
        for (int i = 0; i < 4; ++i) {
            const int k = kg * 4 + i;
            bfx0[nt][i] = (f16_t)(gok ? W_ih[g * IN_DIM + k] : 0.f);                  // cols 0..15
            bfx1[nt][i] = (f16_t)((gok && k >= 5) ? W_ih[g * IN_DIM + 11 + k] : 0.f); // cols 16..26
            bfh[nt][i]  = (f16_t)((gok && k < H_DIM) ? W_hh[g * H_DIM + k] : 0.f);    // units 0..9
        }
    }

    f16_t* tb = &s_h[w][0];
    {   // zero exactly the slots the A_h reads touch (h0 = 0)
        f16x4 z = {(f16_t)0.f, (f16_t)0.f, (f16_t)0.f, (f16_t)0.f};
        *(f16x4*)(tb + bn * 20 + kg * 4) = z;
    }

    float c[4];
#pragma unroll
    for (int r = 0; r < 4; ++r) c[r] = 0.f;

    // x addressing: A row = elem bn; ks0 at col kg*4, ks1 at col 11+kg*4
    const float* xbase = word + (size_t)(e0 + bn) * IN_DIM;
    const size_t tstep = (size_t)BATCH * IN_DIM;
    const int c0 = kg * 4, c1 = 11 + kg * 4;

    f32x4 xa = load4u(xbase + c0);
    f32x4 xb = load4u(xbase + c1);

    for (int t = 0; t < T_STEPS; ++t) {
        // ---- prefetch next step's x (clamped re-read on last iter: L1-hot) ----
        const float* xr = xbase + (size_t)((t + 1 < T_STEPS) ? t + 1 : t) * tstep;
        f32x4 na = load4u(xr + c0);
        f32x4 nb = load4u(xr + c1);

        // ---- previous h as A-fragment: A[row=bn=elem][k=kg*4+i=unit] ----
        const f16x4 ah = *(const f16x4*)(tb + bn * 20 + kg * 4);

        // ---- current x -> f16 A-fragments ----
        f16x4 ax0, ax1;
#pragma unroll
        for (int i = 0; i < 4; ++i) { ax0[i] = (f16_t)xa[i]; ax1[i] = (f16_t)xb[i]; }

        // ---- gates = bias + X@Wih^T + H@Whh^T  (12 MFMA, weights resident) ----
        f32x4 acc[4];
#pragma unroll
        for (int nt = 0; nt < 4; ++nt) {
            f32x4 a = {bias[nt], bias[nt], bias[nt], bias[nt]};
            a = __builtin_amdgcn_mfma_f32_16x16x16f16(ax0, bfx0[nt], a, 0, 0, 0);
            a = __builtin_amdgcn_mfma_f32_16x16x16f16(ax1, bfx1[nt], a, 0, 0, 0);
            a = __builtin_amdgcn_mfma_f32_16x16x16f16(ah,  bfh[nt],  a, 0, 0, 0);
            acc[nt] = a;
        }

        // ---- update: lane owns (elem kg*4+reg, unit bn); all 4 types local ----
#pragma unroll
        for (int reg = 0; reg < 4; ++reg) {
            const float iv = fast_sigmoid(acc[0][reg]);
            const float fv = fast_sigmoid(acc[1][reg]);
            const float gv = fast_tanh   (acc[2][reg]);
            const float ov = fast_sigmoid(acc[3][reg]);
            const float cn = fmaf(fv, c[reg], iv * gv);
            c[reg] = fmaxf(cn, 0.f);                  // relu'd carry
            const float hv = ov * fast_tanh(c[reg]);  // >=0: relu(h) == h
            tb[(kg * 4 + reg) * 20 + bn] = (f16_t)hv; // C-layout -> table
        }

        xa = na; xb = nb;
    }

    // ---- head on lanes 0..15 (one per elem) ----
    if (lane < 16) {
        float hv[H_DIM];
#pragma unroll
        for (int u = 0; u < H_DIM; ++u) hv[u] = (float)tb[lane * 20 + u];
        float accv = b_out[0];
#pragma unroll
        for (int p = 0; p < H2_DIM; ++p) {
            float y = b_fc[p];
#pragma unroll
            for (int m = 0; m < H_DIM; ++m) y = fmaf(W_fc[p * H_DIM + m], hv[m], y);
            y = fmaxf(y, 0.f);
            accv = fmaf(W_out[p], y, accv);
        }
        out[e0 + lane] = fast_sigmoid(accv);
    }
}

extern "C" void kernel_launch(void* const* d_in, const int* in_sizes, int n_in,
                              void* d_out, int out_size, void* d_ws, size_t ws_size,
                              hipStream_t stream) {
    const float* word  = (const float*)d_in[0];
    const float* W_ih  = (const float*)d_in[1];
    const float* W_hh  = (const float*)d_in[2];
    const float* b_ih  = (const float*)d_in[3];
    const float* b_hh  = (const float*)d_in[4];
    const float* W_fc  = (const float*)d_in[5];
    const float* b_fc  = (const float*)d_in[6];
    const float* W_out = (const float*)d_in[7];
    const float* b_out = (const float*)d_in[8];
    float* out = (float*)d_out;

    // 16 elems/wave, 4 waves/block -> 64 elems/block -> 1024 blocks (4/CU)
    lstm_fused_mfma<<<BATCH / 64, 256, 0, stream>>>(
        word, W_ih, W_hh, b_ih, b_hh, W_fc, b_fc, W_out, b_out, out);
}